// Round 1
// baseline (1540.514 us; speedup 1.0000x reference)
//
#include <hip/hip_runtime.h>
#include <cstdint>
#include <cstddef>

#define BS 8
#define SEQ 1024
#define DMODEL 512
#define NHEADS 8
#define DHEAD 64
#define QBLK 32
#define KBLK 64

// C[r][c] = sum_d A[r][d] * W[c][d] (+ bias[c])
// headLayout=1: write C into [b][h][l][dd] layout (b=r>>10, l=r&1023, h=c>>6, dd=c&63)
// headLayout=0: plain row-major [M][512]
__global__ __launch_bounds__(256) void gemm_wt(
    const float* __restrict__ A, const float* __restrict__ W,
    const float* __restrict__ bias, float* __restrict__ C, int headLayout)
{
    __shared__ float As[16][65];
    __shared__ float Ws[16][65];
    const int bm = blockIdx.y * 64;
    const int bn = blockIdx.x * 64;
    const int tid = threadIdx.x;
    const int tx = tid & 15, ty = tid >> 4;
    const int lr = tid >> 2;          // 0..63
    const int lk = (tid & 3) << 2;    // 0,4,8,12

    float acc[4][4];
#pragma unroll
    for (int i = 0; i < 4; ++i)
#pragma unroll
        for (int j = 0; j < 4; ++j) acc[i][j] = 0.f;

    for (int k0 = 0; k0 < DMODEL; k0 += 16) {
        const float4 a4 = *(const float4*)&A[(size_t)(bm + lr) * DMODEL + k0 + lk];
        const float4 w4 = *(const float4*)&W[(size_t)(bn + lr) * DMODEL + k0 + lk];
        As[lk + 0][lr] = a4.x; As[lk + 1][lr] = a4.y; As[lk + 2][lr] = a4.z; As[lk + 3][lr] = a4.w;
        Ws[lk + 0][lr] = w4.x; Ws[lk + 1][lr] = w4.y; Ws[lk + 2][lr] = w4.z; Ws[lk + 3][lr] = w4.w;
        __syncthreads();
#pragma unroll
        for (int kk = 0; kk < 16; ++kk) {
            const float a0 = As[kk][ty * 4 + 0], a1 = As[kk][ty * 4 + 1];
            const float a2 = As[kk][ty * 4 + 2], a3 = As[kk][ty * 4 + 3];
            const float b0 = Ws[kk][tx * 4 + 0], b1 = Ws[kk][tx * 4 + 1];
            const float b2 = Ws[kk][tx * 4 + 2], b3 = Ws[kk][tx * 4 + 3];
            acc[0][0] += a0 * b0; acc[0][1] += a0 * b1; acc[0][2] += a0 * b2; acc[0][3] += a0 * b3;
            acc[1][0] += a1 * b0; acc[1][1] += a1 * b1; acc[1][2] += a1 * b2; acc[1][3] += a1 * b3;
            acc[2][0] += a2 * b0; acc[2][1] += a2 * b1; acc[2][2] += a2 * b2; acc[2][3] += a2 * b3;
            acc[3][0] += a3 * b0; acc[3][1] += a3 * b1; acc[3][2] += a3 * b2; acc[3][3] += a3 * b3;
        }
        __syncthreads();
    }

#pragma unroll
    for (int i = 0; i < 4; ++i) {
        const int r = bm + ty * 4 + i;
        const int b = r >> 10;
        const int l = r & (SEQ - 1);
#pragma unroll
        for (int j = 0; j < 4; ++j) {
            const int c = bn + tx * 4 + j;
            float v = acc[i][j];
            if (bias) v += bias[c];
            if (headLayout) {
                const int h = c >> 6, dd = c & 63;
                C[((size_t)(b * NHEADS + h) * SEQ + l) * DHEAD + dd] = v;
            } else {
                C[(size_t)r * DMODEL + c] = v;
            }
        }
    }
}

// One block per (q-tile of 32 rows, head, batch). 256 threads.
// Full 32x1024 score tile in LDS; sparsemax via Newton on tau; PV on the fly.
__global__ __launch_bounds__(256) void attn_sparsemax(
    const float* __restrict__ Q, const float* __restrict__ K,
    const float* __restrict__ V, float* __restrict__ R)
{
    __shared__ float S[QBLK][SEQ + 1];        // stride 1025 (odd) -> conflict-free column walks
    __shared__ float Qs[QBLK][DHEAD + 1];
    __shared__ float KV[KBLK][DHEAD + 1];
    __shared__ float tau_s[QBLK];

    const int tid = threadIdx.x;
    const int q0 = blockIdx.x * QBLK;
    const int h = blockIdx.y, b = blockIdx.z;
    const size_t base = (size_t)(b * NHEADS + h) * SEQ * DHEAD;
    const float* __restrict__ Qp = Q + base + (size_t)q0 * DHEAD;
    const float* __restrict__ Kp = K + base;
    const float* __restrict__ Vp = V + base;

    // stage Q tile (32 x 64)
    for (int i = tid; i < QBLK * (DHEAD / 4); i += 256) {
        const int q = i >> 4;
        const int dd = (i & 15) << 2;
        const float4 v4 = *(const float4*)&Qp[(size_t)q * DHEAD + dd];
        Qs[q][dd + 0] = v4.x; Qs[q][dd + 1] = v4.y; Qs[q][dd + 2] = v4.z; Qs[q][dd + 3] = v4.w;
    }

    const int tx = tid & 15;   // k-group (4 keys) / d-group (4 dims)
    const int ty = tid >> 4;   // q-group (2 rows)
    const float invT = 0.125f; // 1/sqrt(64)

    // ---- scores: S[q][k] = (q . k) / 8 ----
    for (int kt = 0; kt < SEQ; kt += KBLK) {
        __syncthreads();  // KV reuse fence (also covers Qs on first iter)
        for (int i = tid; i < KBLK * (DHEAD / 4); i += 256) {
            const int kk = i >> 4;
            const int dd = (i & 15) << 2;
            const float4 v4 = *(const float4*)&Kp[(size_t)(kt + kk) * DHEAD + dd];
            KV[kk][dd + 0] = v4.x; KV[kk][dd + 1] = v4.y; KV[kk][dd + 2] = v4.z; KV[kk][dd + 3] = v4.w;
        }
        __syncthreads();
        float a00 = 0, a01 = 0, a02 = 0, a03 = 0, a10 = 0, a11 = 0, a12 = 0, a13 = 0;
#pragma unroll 8
        for (int dd = 0; dd < DHEAD; ++dd) {
            const float qa = Qs[ty * 2 + 0][dd];
            const float qb = Qs[ty * 2 + 1][dd];
            const float k0 = KV[tx * 4 + 0][dd];
            const float k1 = KV[tx * 4 + 1][dd];
            const float k2 = KV[tx * 4 + 2][dd];
            const float k3 = KV[tx * 4 + 3][dd];
            a00 += qa * k0; a01 += qa * k1; a02 += qa * k2; a03 += qa * k3;
            a10 += qb * k0; a11 += qb * k1; a12 += qb * k2; a13 += qb * k3;
        }
        S[ty * 2 + 0][kt + tx * 4 + 0] = a00 * invT;
        S[ty * 2 + 0][kt + tx * 4 + 1] = a01 * invT;
        S[ty * 2 + 0][kt + tx * 4 + 2] = a02 * invT;
        S[ty * 2 + 0][kt + tx * 4 + 3] = a03 * invT;
        S[ty * 2 + 1][kt + tx * 4 + 0] = a10 * invT;
        S[ty * 2 + 1][kt + tx * 4 + 1] = a11 * invT;
        S[ty * 2 + 1][kt + tx * 4 + 2] = a12 * invT;
        S[ty * 2 + 1][kt + tx * 4 + 3] = a13 * invT;
    }
    __syncthreads();

    // ---- sparsemax: find tau with sum(relu(z - tau)) = 1, 8 threads per row ----
    {
        const int row = tid >> 3;
        const int lane = tid & 7;
        float m = -3.0e38f;
#pragma unroll 8
        for (int j = 0; j < SEQ / 8; ++j) m = fmaxf(m, S[row][lane + j * 8]);
#pragma unroll
        for (int o = 1; o < 8; o <<= 1) m = fmaxf(m, __shfl_xor(m, o));
        float tau = m - 1.0f;   // f(tau0) >= 0; Newton from below converges monotonically
        for (int it = 0; it < 16; ++it) {
            float s = 0.f, cnt = 0.f;
#pragma unroll 8
            for (int j = 0; j < SEQ / 8; ++j) {
                const float z = S[row][lane + j * 8];
                if (z > tau) { s += z; cnt += 1.f; }
            }
#pragma unroll
            for (int o = 1; o < 8; o <<= 1) {
                s += __shfl_xor(s, o);
                cnt += __shfl_xor(cnt, o);
            }
            tau = (s - 1.f) / cnt;   // cnt >= 1 always (tau < row max)
        }
        if (lane == 0) tau_s[row] = tau;
    }
    __syncthreads();

    // ---- PV: res[q][d] = sum_k relu(S[q][k] - tau[q]) * V[k][d] ----
    const float tau0 = tau_s[ty * 2 + 0];
    const float tau1 = tau_s[ty * 2 + 1];
    float r00 = 0, r01 = 0, r02 = 0, r03 = 0, r10 = 0, r11 = 0, r12 = 0, r13 = 0;
    for (int kt = 0; kt < SEQ; kt += KBLK) {
        __syncthreads();  // KV reuse fence
        for (int i = tid; i < KBLK * (DHEAD / 4); i += 256) {
            const int kk = i >> 4;
            const int dd = (i & 15) << 2;
            const float4 v4 = *(const float4*)&Vp[(size_t)(kt + kk) * DHEAD + dd];
            KV[kk][dd + 0] = v4.x; KV[kk][dd + 1] = v4.y; KV[kk][dd + 2] = v4.z; KV[kk][dd + 3] = v4.w;
        }
        __syncthreads();
#pragma unroll 4
        for (int kk = 0; kk < KBLK; ++kk) {
            const float p0 = fmaxf(S[ty * 2 + 0][kt + kk] - tau0, 0.f);
            const float p1 = fmaxf(S[ty * 2 + 1][kt + kk] - tau1, 0.f);
            const float v0 = KV[kk][tx * 4 + 0];
            const float v1 = KV[kk][tx * 4 + 1];
            const float v2 = KV[kk][tx * 4 + 2];
            const float v3 = KV[kk][tx * 4 + 3];
            r00 += p0 * v0; r01 += p0 * v1; r02 += p0 * v2; r03 += p0 * v3;
            r10 += p1 * v0; r11 += p1 * v1; r12 += p1 * v2; r13 += p1 * v3;
        }
    }

    // write R in [b][l][h*64+d] layout (row-major 8192x512) for the final GEMM
    const int outc = h * DHEAD + tx * 4;
    {
        const int q = q0 + ty * 2;
        float4 o0 = make_float4(r00, r01, r02, r03);
        *(float4*)&R[((size_t)b * SEQ + q) * DMODEL + outc] = o0;
        float4 o1 = make_float4(r10, r11, r12, r13);
        *(float4*)&R[((size_t)b * SEQ + q + 1) * DMODEL + outc] = o1;
    }
}

extern "C" void kernel_launch(void* const* d_in, const int* in_sizes, int n_in,
                              void* d_out, int out_size, void* d_ws, size_t ws_size,
                              hipStream_t stream) {
    const float* h_q = (const float*)d_in[0];
    const float* h_k = (const float*)d_in[1];
    const float* h_v = (const float*)d_in[2];
    const float* Wq  = (const float*)d_in[3];
    const float* Wk  = (const float*)d_in[4];
    const float* Wv  = (const float*)d_in[5];
    const float* bv  = (const float*)d_in[6];
    const float* Wf  = (const float*)d_in[7];
    const float* bf  = (const float*)d_in[8];
    float* out = (float*)d_out;

    const size_t perTensor = (size_t)BS * NHEADS * SEQ * DHEAD;  // 4,194,304 floats
    float* Qws = (float*)d_ws;
    float* Kws = Qws + perTensor;
    float* Vws = Kws + perTensor;
    float* Rws = Vws + perTensor;

    const dim3 gemmGrid(DMODEL / 64, (BS * SEQ) / 64, 1);   // 8 x 128
    const dim3 attnGrid(SEQ / QBLK, NHEADS, BS);            // 32 x 8 x 8
    const dim3 blk(256, 1, 1);

    gemm_wt<<<gemmGrid, blk, 0, stream>>>(h_q, Wq, nullptr, Qws, 1);
    gemm_wt<<<gemmGrid, blk, 0, stream>>>(h_k, Wk, nullptr, Kws, 1);
    gemm_wt<<<gemmGrid, blk, 0, stream>>>(h_v, Wv, bv, Vws, 1);
    attn_sparsemax<<<attnGrid, blk, 0, stream>>>(Qws, Kws, Vws, Rws);
    gemm_wt<<<gemmGrid, blk, 0, stream>>>(Rws, Wf, bf, out, 0);
}

// Round 3
// 1349.577 us; speedup vs baseline: 1.1415x; 1.1415x over previous
//
#include <hip/hip_runtime.h>
#include <hip/hip_bf16.h>
#include <cstdint>
#include <cstddef>

#define BS 8
#define SEQ 1024
#define DMODEL 512
#define NHEADS 8
#define DHEAD 64
#define SPAD 1028   // S row stride (floats); 1028%32==4 keeps MFMA-write columns spread

typedef float f32x4 __attribute__((ext_vector_type(4)));
typedef short bf16x8 __attribute__((ext_vector_type(8)));

static __device__ __forceinline__ unsigned short f2bf(float v) {
    __hip_bfloat16 hb = __float2bfloat16(v);
    return *reinterpret_cast<unsigned short*>(&hb);
}

// C[r][c] = sum_d A[r][d] * W[c][d] (+ bias[c]), A: MxK f32 row-major, W: NxK f32.
// mode 0: f32 out row-major [M][512], +bias
// mode 1: bf16 out in [b][h][l][dd] head layout, value*scale, +bias
// mode 3: f32  out in [b][h][l][dd] head layout, value*scale, +bias
__global__ __launch_bounds__(256) void gemm_wt(
    const float* __restrict__ A, const float* __restrict__ W,
    const float* __restrict__ bias, void* __restrict__ Cout, int mode, float scale)
{
    __shared__ float As[16][65];
    __shared__ float Ws[16][65];
    const int bm = blockIdx.y * 64;
    const int bn = blockIdx.x * 64;
    const int tid = threadIdx.x;
    const int tx = tid & 15, ty = tid >> 4;
    const int lr = tid >> 2;          // 0..63
    const int lk = (tid & 3) << 2;    // 0,4,8,12

    float acc[4][4];
#pragma unroll
    for (int i = 0; i < 4; ++i)
#pragma unroll
        for (int j = 0; j < 4; ++j) acc[i][j] = 0.f;

    for (int k0 = 0; k0 < DMODEL; k0 += 16) {
        const float4 a4 = *(const float4*)&A[(size_t)(bm + lr) * DMODEL + k0 + lk];
        const float4 w4 = *(const float4*)&W[(size_t)(bn + lr) * DMODEL + k0 + lk];
        As[lk + 0][lr] = a4.x; As[lk + 1][lr] = a4.y; As[lk + 2][lr] = a4.z; As[lk + 3][lr] = a4.w;
        Ws[lk + 0][lr] = w4.x; Ws[lk + 1][lr] = w4.y; Ws[lk + 2][lr] = w4.z; Ws[lk + 3][lr] = w4.w;
        __syncthreads();
#pragma unroll
        for (int kk = 0; kk < 16; ++kk) {
            const float a0 = As[kk][ty * 4 + 0], a1 = As[kk][ty * 4 + 1];
            const float a2 = As[kk][ty * 4 + 2], a3 = As[kk][ty * 4 + 3];
            const float b0 = Ws[kk][tx * 4 + 0], b1 = Ws[kk][tx * 4 + 1];
            const float b2 = Ws[kk][tx * 4 + 2], b3 = Ws[kk][tx * 4 + 3];
            acc[0][0] += a0 * b0; acc[0][1] += a0 * b1; acc[0][2] += a0 * b2; acc[0][3] += a0 * b3;
            acc[1][0] += a1 * b0; acc[1][1] += a1 * b1; acc[1][2] += a1 * b2; acc[1][3] += a1 * b3;
            acc[2][0] += a2 * b0; acc[2][1] += a2 * b1; acc[2][2] += a2 * b2; acc[2][3] += a2 * b3;
            acc[3][0] += a3 * b0; acc[3][1] += a3 * b1; acc[3][2] += a3 * b2; acc[3][3] += a3 * b3;
        }
        __syncthreads();
    }

    if (mode == 0) {
        float* C = (float*)Cout;
#pragma unroll
        for (int i = 0; i < 4; ++i) {
            const int r = bm + ty * 4 + i;
#pragma unroll
            for (int j = 0; j < 4; ++j) {
                const int c = bn + tx * 4 + j;
                C[(size_t)r * DMODEL + c] = acc[i][j] + (bias ? bias[c] : 0.f);
            }
        }
    } else if (mode == 1) {
        unsigned short* C = (unsigned short*)Cout;
#pragma unroll
        for (int i = 0; i < 4; ++i) {
            const int r = bm + ty * 4 + i;
            const int b = r >> 10;
            const int l = r & (SEQ - 1);
#pragma unroll
            for (int j = 0; j < 4; ++j) {
                const int c = bn + tx * 4 + j;
                const int h = c >> 6, dd = c & 63;
                float v = acc[i][j] * scale + (bias ? bias[c] : 0.f);
                C[((size_t)(b * NHEADS + h) * SEQ + l) * DHEAD + dd] = f2bf(v);
            }
        }
    } else {
        float* C = (float*)Cout;
#pragma unroll
        for (int i = 0; i < 4; ++i) {
            const int r = bm + ty * 4 + i;
            const int b = r >> 10;
            const int l = r & (SEQ - 1);
#pragma unroll
            for (int j = 0; j < 4; ++j) {
                const int c = bn + tx * 4 + j;
                const int h = c >> 6, dd = c & 63;
                float v = acc[i][j] * scale + (bias ? bias[c] : 0.f);
                C[((size_t)(b * NHEADS + h) * SEQ + l) * DHEAD + dd] = v;
            }
        }
    }
}

// Bisect attention: MFMA QK^T (under test) + known-good VALU sparsemax/PV.
// One block per (16 q-rows, head, batch); 4 waves, wave w owns keys [w*256, w*256+256).
__global__ __launch_bounds__(256) void attn_bisect(
    const unsigned short* __restrict__ Q, const unsigned short* __restrict__ K,
    const float* __restrict__ V, float* __restrict__ R)
{
    __shared__ float S[16][SPAD];
    __shared__ float Vs[64][65];
    __shared__ float tau_s[16];

    const int tid = threadIdx.x;
    const int w = tid >> 6;
    const int l = tid & 63;
    const int lr = l & 15, lg = l >> 4;
    const int q0 = blockIdx.x * 16;
    const int h = blockIdx.y, b = blockIdx.z;
    const size_t base = (size_t)(b * NHEADS + h) * SEQ * DHEAD;
    const unsigned short* Qp = Q + base;
    const unsigned short* Kp = K + base;
    const float* Vp = V + base;

    // A-frags: Q[q0+lr][lg*8 + i (+32)]  (Q pre-scaled by 1/TEMPERATURE)
    const bf16x8 aq0 = *(const bf16x8*)(Qp + (size_t)(q0 + lr) * DHEAD + lg * 8);
    const bf16x8 aq1 = *(const bf16x8*)(Qp + (size_t)(q0 + lr) * DHEAD + 32 + lg * 8);

    const int kbase = w * 256;

    // ---- QK^T via MFMA (layout hypothesis under test) ----
    f32x4 acc[16];
#pragma unroll
    for (int t = 0; t < 16; ++t) acc[t] = (f32x4)0.f;
#pragma unroll 4
    for (int t = 0; t < 16; ++t) {
        const unsigned short* kp = Kp + (size_t)(kbase + t * 16 + lr) * DHEAD + lg * 8;
        const bf16x8 bk0 = *(const bf16x8*)(kp);
        const bf16x8 bk1 = *(const bf16x8*)(kp + 32);
        acc[t] = __builtin_amdgcn_mfma_f32_16x16x32_bf16(aq0, bk0, acc[t], 0, 0, 0);
        acc[t] = __builtin_amdgcn_mfma_f32_16x16x32_bf16(aq1, bk1, acc[t], 0, 0, 0);
    }
#pragma unroll
    for (int t = 0; t < 16; ++t)
#pragma unroll
        for (int j = 0; j < 4; ++j)
            S[lg * 4 + j][kbase + t * 16 + lr] = acc[t][j];
    __syncthreads();

    // ---- sparsemax tau: wave w handles rows 4w..4w+3, whole wave per row ----
    for (int rr = 0; rr < 4; ++rr) {
        const int r = w * 4 + rr;
        float z[16];
#pragma unroll
        for (int j = 0; j < 16; ++j) z[j] = S[r][l + j * 64];
        float m = z[0];
#pragma unroll
        for (int j = 1; j < 16; ++j) m = fmaxf(m, z[j]);
#pragma unroll
        for (int o = 32; o >= 1; o >>= 1) m = fmaxf(m, __shfl_xor(m, o));
        float tau = m - 1.0f;   // f(tau0) >= 0 -> monotone Newton from below
        for (int it = 0; it < 32; ++it) {
            float s = 0.f, cnt = 0.f;
#pragma unroll
            for (int j = 0; j < 16; ++j) {
                if (z[j] > tau) { s += z[j]; cnt += 1.f; }
            }
#pragma unroll
            for (int o = 32; o >= 1; o >>= 1) {
                s += __shfl_xor(s, o);
                cnt += __shfl_xor(cnt, o);
            }
            const float tn = (s - 1.f) / cnt;   // cnt >= 1 always (tau < row max)
            if (tn == tau) break;
            tau = tn;
        }
        if (l == 0) tau_s[r] = tau;
    }
    __syncthreads();

    // ---- VALU PV (round-1-proven pattern): thread (ty,tx) owns q=ty, d=tx*4..tx*4+3 ----
    const int ty = tid >> 4;   // q row 0..15
    const int tx = tid & 15;   // d group
    const float tq = tau_s[ty];
    float r0 = 0.f, r1 = 0.f, r2 = 0.f, r3 = 0.f;
    for (int kt = 0; kt < SEQ; kt += 64) {
        __syncthreads();  // Vs reuse fence
        for (int i = tid; i < 64 * 16; i += 256) {
            const int kk = i >> 4;
            const int dd = (i & 15) << 2;
            const float4 v4 = *(const float4*)&Vp[(size_t)(kt + kk) * DHEAD + dd];
            Vs[kk][dd + 0] = v4.x; Vs[kk][dd + 1] = v4.y; Vs[kk][dd + 2] = v4.z; Vs[kk][dd + 3] = v4.w;
        }
        __syncthreads();
#pragma unroll 4
        for (int kk = 0; kk < 64; ++kk) {
            const float p = fmaxf(S[ty][kt + kk] - tq, 0.f);
            r0 += p * Vs[kk][tx * 4 + 0];
            r1 += p * Vs[kk][tx * 4 + 1];
            r2 += p * Vs[kk][tx * 4 + 2];
            r3 += p * Vs[kk][tx * 4 + 3];
        }
    }

    float4 o4 = make_float4(r0, r1, r2, r3);
    *(float4*)&R[((size_t)b * SEQ + q0 + ty) * DMODEL + h * DHEAD + tx * 4] = o4;
}

extern "C" void kernel_launch(void* const* d_in, const int* in_sizes, int n_in,
                              void* d_out, int out_size, void* d_ws, size_t ws_size,
                              hipStream_t stream) {
    const float* h_q = (const float*)d_in[0];
    const float* h_k = (const float*)d_in[1];
    const float* h_v = (const float*)d_in[2];
    const float* Wq  = (const float*)d_in[3];
    const float* Wk  = (const float*)d_in[4];
    const float* Wv  = (const float*)d_in[5];
    const float* bv  = (const float*)d_in[6];
    const float* Wf  = (const float*)d_in[7];
    const float* bf  = (const float*)d_in[8];
    float* out = (float*)d_out;

    const size_t perT = (size_t)BS * NHEADS * SEQ * DHEAD;   // 4,194,304 elements
    unsigned short* Qws = (unsigned short*)d_ws;             // bf16, 8 MB
    unsigned short* Kws = Qws + perT;                        // bf16, 8 MB
    float* Vws = (float*)(Kws + perT);                       // f32, 16 MB
    float* Rws = Vws + perT;                                 // f32, 16 MB

    const dim3 gemmGrid(DMODEL / 64, (BS * SEQ) / 64, 1);    // 8 x 128
    const dim3 attnGrid(SEQ / 16, NHEADS, BS);               // 64 x 8 x 8
    const dim3 blk(256, 1, 1);

    gemm_wt<<<gemmGrid, blk, 0, stream>>>(h_q, Wq, nullptr, Qws, 1, 0.125f);
    gemm_wt<<<gemmGrid, blk, 0, stream>>>(h_k, Wk, nullptr, Kws, 1, 1.0f);
    gemm_wt<<<gemmGrid, blk, 0, stream>>>(h_v, Wv, bv,      Vws, 3, 1.0f);
    attn_bisect<<<attnGrid, blk, 0, stream>>>(Qws, Kws, Vws, Rws);
    gemm_wt<<<gemmGrid, blk, 0, stream>>>(Rws, Wf, bf, out, 0, 1.0f);
}

// Round 4
// 538.708 us; speedup vs baseline: 2.8596x; 2.5052x over previous
//
#include <hip/hip_runtime.h>
#include <hip/hip_bf16.h>
#include <cstdint>
#include <cstddef>

#define BS 8
#define SEQ 1024
#define DMODEL 512
#define NHEADS 8
#define DHEAD 64
#define QBLK 32
#define SPAD 1028   // f32 S row stride: 4112 B (16B-aligned, non-pow2 bank spread)
#define VTS 40      // Vt row stride in shorts: 80 B (16B-aligned, 20-dword bank spread)

typedef float f32x4 __attribute__((ext_vector_type(4)));
typedef short bf16x8 __attribute__((ext_vector_type(8)));

static __device__ __forceinline__ unsigned short f2bf(float v) {
    __hip_bfloat16 hb = __float2bfloat16(v);
    return *reinterpret_cast<unsigned short*>(&hb);
}

// ---------------------------------------------------------------------------
// MFMA GEMM: C[r][c] = sum_k A[r][k] * W[c][k]   (A: Mx512, W: 512x512)
// A is f32 (abf16=0) or bf16 (abf16=1); W always f32 (converted on the fly).
// mode 0: f32 out row-major [M][512], + bias
// mode 1: bf16 out head layout [b][h][l][dd], value*scale + bias
// Fragment contract validated on HW (round-3 bisect):
//   xfrag lane: X[row=lr][k=lg*8+i]; yfrag lane: Y[row=lr][k=lg*8+i]
//   => reg j = (X*Y^T)[lg*4+j][lr]
// ---------------------------------------------------------------------------
__global__ __launch_bounds__(256) void mfma_gemm(
    const void* __restrict__ Ain, const float* __restrict__ W,
    const float* __restrict__ bias, void* __restrict__ Cout,
    int mode, float scale, int abf16)
{
    __shared__ __align__(16) unsigned short As[64][72];
    __shared__ __align__(16) unsigned short Bs[64][72];

    const int tid = threadIdx.x;
    const int w = tid >> 6, l = tid & 63, lr = l & 15, lg = l >> 4;
    const int bm = blockIdx.y * 64, bn = blockIdx.x * 64;
    const int sr = tid & 63;   // staging row 0..63
    const int sc = tid >> 6;   // staging col-group (16 elems)
    const int mrow = 32 * (w & 1);
    const int ncol = 32 * (w >> 1);

    f32x4 acc[2][2];
    acc[0][0] = (f32x4)0.f; acc[0][1] = (f32x4)0.f;
    acc[1][0] = (f32x4)0.f; acc[1][1] = (f32x4)0.f;

    for (int k0 = 0; k0 < DMODEL; k0 += 64) {
        unsigned short abuf[16], wbuf[16];
        if (abf16) {
            const uint4* ap = (const uint4*)((const unsigned short*)Ain +
                               (size_t)(bm + sr) * DMODEL + k0 + sc * 16);
            *(uint4*)&abuf[0] = ap[0];
            *(uint4*)&abuf[8] = ap[1];
        } else {
            const float* ap = (const float*)Ain + (size_t)(bm + sr) * DMODEL + k0 + sc * 16;
#pragma unroll
            for (int j = 0; j < 4; ++j) {
                const float4 f = *(const float4*)(ap + j * 4);
                abuf[j*4+0] = f2bf(f.x); abuf[j*4+1] = f2bf(f.y);
                abuf[j*4+2] = f2bf(f.z); abuf[j*4+3] = f2bf(f.w);
            }
        }
        {
            const float* wp = W + (size_t)(bn + sr) * DMODEL + k0 + sc * 16;
#pragma unroll
            for (int j = 0; j < 4; ++j) {
                const float4 f = *(const float4*)(wp + j * 4);
                wbuf[j*4+0] = f2bf(f.x); wbuf[j*4+1] = f2bf(f.y);
                wbuf[j*4+2] = f2bf(f.z); wbuf[j*4+3] = f2bf(f.w);
            }
        }
        __syncthreads();   // prior-iteration frag reads complete
        *(uint4*)&As[sr][sc * 16 + 0] = *(uint4*)&abuf[0];
        *(uint4*)&As[sr][sc * 16 + 8] = *(uint4*)&abuf[8];
        *(uint4*)&Bs[sr][sc * 16 + 0] = *(uint4*)&wbuf[0];
        *(uint4*)&Bs[sr][sc * 16 + 8] = *(uint4*)&wbuf[8];
        __syncthreads();
#pragma unroll
        for (int kh = 0; kh < 2; ++kh) {
            const bf16x8 a0 = *(const bf16x8*)&As[mrow + lr][kh * 32 + lg * 8];
            const bf16x8 a1 = *(const bf16x8*)&As[mrow + 16 + lr][kh * 32 + lg * 8];
            const bf16x8 b0 = *(const bf16x8*)&Bs[ncol + lr][kh * 32 + lg * 8];
            const bf16x8 b1 = *(const bf16x8*)&Bs[ncol + 16 + lr][kh * 32 + lg * 8];
            acc[0][0] = __builtin_amdgcn_mfma_f32_16x16x32_bf16(a0, b0, acc[0][0], 0, 0, 0);
            acc[0][1] = __builtin_amdgcn_mfma_f32_16x16x32_bf16(a0, b1, acc[0][1], 0, 0, 0);
            acc[1][0] = __builtin_amdgcn_mfma_f32_16x16x32_bf16(a1, b0, acc[1][0], 0, 0, 0);
            acc[1][1] = __builtin_amdgcn_mfma_f32_16x16x32_bf16(a1, b1, acc[1][1], 0, 0, 0);
        }
    }

#pragma unroll
    for (int mt = 0; mt < 2; ++mt)
#pragma unroll
    for (int nt = 0; nt < 2; ++nt)
#pragma unroll
    for (int j = 0; j < 4; ++j) {
        const int r = bm + mrow + mt * 16 + lg * 4 + j;
        const int c = bn + ncol + nt * 16 + lr;
        const float v = acc[mt][nt][j] * scale + (bias ? bias[c] : 0.f);
        if (mode == 0) {
            ((float*)Cout)[(size_t)r * DMODEL + c] = v;
        } else {
            const int b = r >> 10, ll = r & (SEQ - 1);
            const int h = c >> 6, dd = c & 63;
            ((unsigned short*)Cout)[((size_t)(b * NHEADS + h) * SEQ + ll) * DHEAD + dd] = f2bf(v);
        }
    }
}

// ---------------------------------------------------------------------------
// MFMA sparsemax attention. Block = (32 q-rows, head, batch), 512 threads.
// QK^T: wave w -> q-half (w>>2)*16, key slice (w&3)*256. S f32 in LDS.
// Sparsemax: exact Newton on tau (monotone from max-1), wave per row.
// PV: wave w owns output tile (q-half (w>>2)*16, d-cols (w&3)*16); V staged
// transposed in double-buffered LDS tiles (32 keys), distance-2 prefetch.
// ---------------------------------------------------------------------------
__global__ __launch_bounds__(512) void attn_mfma(
    const unsigned short* __restrict__ Q, const unsigned short* __restrict__ K,
    const unsigned short* __restrict__ V, unsigned short* __restrict__ R)
{
    __shared__ __align__(16) float S[QBLK][SPAD];
    __shared__ __align__(16) unsigned short Vt[2][64][VTS];
    __shared__ float tau_s[QBLK];

    const int tid = threadIdx.x;
    const int w = tid >> 6, l = tid & 63, lr = l & 15, lg = l >> 4;
    const int q0 = blockIdx.x * QBLK;
    const int h = blockIdx.y, b = blockIdx.z;
    const size_t base = (size_t)(b * NHEADS + h) * SEQ * DHEAD;
    const unsigned short* Qp = Q + base;
    const unsigned short* Kp = K + base;
    const unsigned short* Vp = V + base;

    const int qh = (w >> 2) * 16;   // wave's q-row half
    const int ks = (w & 3) * 256;   // wave's QK key slice

    // V prefetch lanes: 512 threads cover one 32x64 tile (one uint2 each)
    const int vrow = tid & 31;      // key-local
    const int vcg = tid >> 5;       // d-group of 4 (0..15)
    uint2 vrA = *(const uint2*)(Vp + (size_t)(0 * 32 + vrow) * DHEAD + vcg * 4);
    uint2 vrB = *(const uint2*)(Vp + (size_t)(1 * 32 + vrow) * DHEAD + vcg * 4);

    // ---- QK^T (validated contract) ----
    const bf16x8 aq0 = *(const bf16x8*)(Qp + (size_t)(q0 + qh + lr) * DHEAD + lg * 8);
    const bf16x8 aq1 = *(const bf16x8*)(Qp + (size_t)(q0 + qh + lr) * DHEAD + 32 + lg * 8);
    {
        f32x4 acc[16];
#pragma unroll
        for (int t = 0; t < 16; ++t) acc[t] = (f32x4)0.f;
#pragma unroll 4
        for (int t = 0; t < 16; ++t) {
            const unsigned short* kp = Kp + (size_t)(ks + t * 16 + lr) * DHEAD + lg * 8;
            const bf16x8 bk0 = *(const bf16x8*)(kp);
            const bf16x8 bk1 = *(const bf16x8*)(kp + 32);
            acc[t] = __builtin_amdgcn_mfma_f32_16x16x32_bf16(aq0, bk0, acc[t], 0, 0, 0);
            acc[t] = __builtin_amdgcn_mfma_f32_16x16x32_bf16(aq1, bk1, acc[t], 0, 0, 0);
        }
#pragma unroll
        for (int t = 0; t < 16; ++t)
#pragma unroll
            for (int j = 0; j < 4; ++j)
                S[qh + lg * 4 + j][ks + t * 16 + lr] = acc[t][j];
    }
    __syncthreads();   // S complete

    // stage tile 0 (overlaps sparsemax)
    {
        const unsigned short* pv = (const unsigned short*)&vrA;
#pragma unroll
        for (int i = 0; i < 4; ++i) Vt[0][vcg * 4 + i][vrow] = pv[i];
    }

    // ---- sparsemax: wave w rows 4w..4w+3 (validated) ----
    for (int rr = 0; rr < 4; ++rr) {
        const int r = w * 4 + rr;
        float z[16];
#pragma unroll
        for (int j = 0; j < 16; ++j) z[j] = S[r][l + j * 64];
        float m = z[0];
#pragma unroll
        for (int j = 1; j < 16; ++j) m = fmaxf(m, z[j]);
#pragma unroll
        for (int o = 32; o >= 1; o >>= 1) m = fmaxf(m, __shfl_xor(m, o));
        float tau = m - 1.0f;
        for (int it = 0; it < 32; ++it) {
            float s = 0.f, cnt = 0.f;
#pragma unroll
            for (int j = 0; j < 16; ++j)
                if (z[j] > tau) { s += z[j]; cnt += 1.f; }
#pragma unroll
            for (int o = 32; o >= 1; o >>= 1) {
                s += __shfl_xor(s, o);
                cnt += __shfl_xor(cnt, o);
            }
            const float tn = (s - 1.f) / cnt;   // cnt >= 1 always
            if (tn == tau) break;
            tau = tn;
        }
        if (l == 0) tau_s[r] = tau;
    }
    __syncthreads();   // tau + Vt[0] ready

    // ---- PV: wave tile (qh, dcol), double-buffered Vt, 1 barrier per k-tile ----
    const float taur = tau_s[qh + lr];
    const int dcol = (w & 3) * 16;
    f32x4 o = (f32x4)0.f;

#define PV_COMPUTE(KT, BUF)                                                    \
    {                                                                          \
        const float* sp = &S[qh + lr][(KT) * 32 + lg * 8];                     \
        const f32x4 s0 = *(const f32x4*)sp;                                    \
        const f32x4 s1 = *(const f32x4*)(sp + 4);                              \
        bf16x8 pa;                                                             \
        _Pragma("unroll")                                                      \
        for (int i = 0; i < 4; ++i) {                                          \
            pa[i]     = (short)f2bf(fmaxf(s0[i] - taur, 0.f));                 \
            pa[i + 4] = (short)f2bf(fmaxf(s1[i] - taur, 0.f));                 \
        }                                                                      \
        const bf16x8 vb = *(const bf16x8*)&Vt[BUF][dcol + lr][lg * 8];         \
        o = __builtin_amdgcn_mfma_f32_16x16x32_bf16(pa, vb, o, 0, 0, 0);       \
    }
#define VT_WRITE(BUF, REG)                                                     \
    {                                                                          \
        const unsigned short* pv = (const unsigned short*)&(REG);              \
        _Pragma("unroll")                                                      \
        for (int i = 0; i < 4; ++i) Vt[BUF][vcg * 4 + i][vrow] = pv[i];        \
    }

    for (int kt = 0; kt < 32; kt += 2) {
        if (kt + 2 < 32)
            vrA = *(const uint2*)(Vp + (size_t)((kt + 2) * 32 + vrow) * DHEAD + vcg * 4);
        PV_COMPUTE(kt, 0)
        if (kt + 1 < 32) VT_WRITE(1, vrB)
        __syncthreads();
        if (kt + 3 < 32)
            vrB = *(const uint2*)(Vp + (size_t)((kt + 3) * 32 + vrow) * DHEAD + vcg * 4);
        PV_COMPUTE(kt + 1, 1)
        if (kt + 2 < 32) VT_WRITE(0, vrA)
        __syncthreads();
    }

    // ---- write O tile: rows qh+lg*4+j, cols dcol+lr (bf16 R for final GEMM) ----
#pragma unroll
    for (int j = 0; j < 4; ++j)
        R[((size_t)b * SEQ + q0 + qh + lg * 4 + j) * DMODEL + h * DHEAD + dcol + lr] =
            f2bf(o[j]);
}

extern "C" void kernel_launch(void* const* d_in, const int* in_sizes, int n_in,
                              void* d_out, int out_size, void* d_ws, size_t ws_size,
                              hipStream_t stream) {
    const float* h_q = (const float*)d_in[0];
    const float* h_k = (const float*)d_in[1];
    const float* h_v = (const float*)d_in[2];
    const float* Wq  = (const float*)d_in[3];
    const float* Wk  = (const float*)d_in[4];
    const float* Wv  = (const float*)d_in[5];
    const float* bv  = (const float*)d_in[6];
    const float* Wf  = (const float*)d_in[7];
    const float* bf  = (const float*)d_in[8];
    float* out = (float*)d_out;

    const size_t perT = (size_t)BS * NHEADS * SEQ * DHEAD;   // 4,194,304 elements
    unsigned short* Qws = (unsigned short*)d_ws;             // bf16 8.4 MB
    unsigned short* Kws = Qws + perT;
    unsigned short* Vws = Kws + perT;
    unsigned short* Rws = Vws + perT;                        // bf16 attn output

    const dim3 gemmGrid(DMODEL / 64, (BS * SEQ) / 64, 1);    // 8 x 128
    const dim3 attnGrid(SEQ / QBLK, NHEADS, BS);             // 32 x 8 x 8

    mfma_gemm<<<gemmGrid, 256, 0, stream>>>(h_q, Wq, nullptr, Qws, 1, 0.125f, 0);
    mfma_gemm<<<gemmGrid, 256, 0, stream>>>(h_k, Wk, nullptr, Kws, 1, 1.0f, 0);
    mfma_gemm<<<gemmGrid, 256, 0, stream>>>(h_v, Wv, bv,      Vws, 1, 1.0f, 0);
    attn_mfma<<<attnGrid, 512, 0, stream>>>(Qws, Kws, Vws, Rws);
    mfma_gemm<<<gemmGrid, 256, 0, stream>>>(Rws, Wf, bf, out, 0, 1.0f, 1);
}

// Round 5
// 387.836 us; speedup vs baseline: 3.9721x; 1.3890x over previous
//
#include <hip/hip_runtime.h>
#include <hip/hip_bf16.h>
#include <cstdint>
#include <cstddef>

#define BS 8
#define SEQ 1024
#define DMODEL 512
#define NHEADS 8
#define DHEAD 64
#define QBLK 16
#define SPAD 1028   // f32 S row stride (dwords); 16B-aligned rows

typedef float f32x4 __attribute__((ext_vector_type(4)));
typedef short bf16x8 __attribute__((ext_vector_type(8)));

static __device__ __forceinline__ unsigned short f2bf(float v) {
    __hip_bfloat16 hb = __float2bfloat16(v);
    return *reinterpret_cast<unsigned short*>(&hb);
}

// ---------------------------------------------------------------------------
// MFMA GEMM: C[r][c] = sum_k A[r][k] * W[c][k]   (A: Mx512 row-major, W: 512x512)
// A f32 (abf16=0) or bf16 (abf16=1); W f32 converted on the fly.
// mode 0: f32 out row-major [M][512] + bias
// mode 1: bf16 out head layout [b][h][l][dd], value*scale + bias
// mode 2: bf16 out TRANSPOSED head layout [b][h][dd][l], value*scale + bias
//         (direct uint2 scatter stores; j=0..3 are consecutive l -> 8B store)
// Fragment contract (HW-validated r3): frag = X[row=lr][k=lg*8+i];
// output reg j = (X*Y^T)[row=lg*4+j][col=lr].
// ---------------------------------------------------------------------------
__global__ __launch_bounds__(256) void mfma_gemm(
    const void* __restrict__ Ain, const float* __restrict__ W,
    const float* __restrict__ bias, void* __restrict__ Cout,
    int mode, float scale, int abf16)
{
    __shared__ __align__(16) unsigned short As[64][72];
    __shared__ __align__(16) unsigned short Bs[64][72];

    const int tid = threadIdx.x;
    const int w = tid >> 6, l = tid & 63, lr = l & 15, lg = l >> 4;
    const int bm = blockIdx.y * 64, bn = blockIdx.x * 64;
    const int sr = tid & 63;   // staging row
    const int sc = tid >> 6;   // staging col-group (16 elems)
    const int mrow = 32 * (w & 1);
    const int ncol = 32 * (w >> 1);

    f32x4 acc[2][2];
    acc[0][0] = (f32x4)0.f; acc[0][1] = (f32x4)0.f;
    acc[1][0] = (f32x4)0.f; acc[1][1] = (f32x4)0.f;

    for (int k0 = 0; k0 < DMODEL; k0 += 64) {
        unsigned short abuf[16], wbuf[16];
        if (abf16) {
            const uint4* ap = (const uint4*)((const unsigned short*)Ain +
                               (size_t)(bm + sr) * DMODEL + k0 + sc * 16);
            *(uint4*)&abuf[0] = ap[0];
            *(uint4*)&abuf[8] = ap[1];
        } else {
            const float* ap = (const float*)Ain + (size_t)(bm + sr) * DMODEL + k0 + sc * 16;
#pragma unroll
            for (int j = 0; j < 4; ++j) {
                const float4 f = *(const float4*)(ap + j * 4);
                abuf[j*4+0] = f2bf(f.x); abuf[j*4+1] = f2bf(f.y);
                abuf[j*4+2] = f2bf(f.z); abuf[j*4+3] = f2bf(f.w);
            }
        }
        {
            const float* wp = W + (size_t)(bn + sr) * DMODEL + k0 + sc * 16;
#pragma unroll
            for (int j = 0; j < 4; ++j) {
                const float4 f = *(const float4*)(wp + j * 4);
                wbuf[j*4+0] = f2bf(f.x); wbuf[j*4+1] = f2bf(f.y);
                wbuf[j*4+2] = f2bf(f.z); wbuf[j*4+3] = f2bf(f.w);
            }
        }
        __syncthreads();
        *(uint4*)&As[sr][sc * 16 + 0] = *(uint4*)&abuf[0];
        *(uint4*)&As[sr][sc * 16 + 8] = *(uint4*)&abuf[8];
        *(uint4*)&Bs[sr][sc * 16 + 0] = *(uint4*)&wbuf[0];
        *(uint4*)&Bs[sr][sc * 16 + 8] = *(uint4*)&wbuf[8];
        __syncthreads();
#pragma unroll
        for (int kh = 0; kh < 2; ++kh) {
            const bf16x8 a0 = *(const bf16x8*)&As[mrow + lr][kh * 32 + lg * 8];
            const bf16x8 a1 = *(const bf16x8*)&As[mrow + 16 + lr][kh * 32 + lg * 8];
            const bf16x8 b0 = *(const bf16x8*)&Bs[ncol + lr][kh * 32 + lg * 8];
            const bf16x8 b1 = *(const bf16x8*)&Bs[ncol + 16 + lr][kh * 32 + lg * 8];
            acc[0][0] = __builtin_amdgcn_mfma_f32_16x16x32_bf16(a0, b0, acc[0][0], 0, 0, 0);
            acc[0][1] = __builtin_amdgcn_mfma_f32_16x16x32_bf16(a0, b1, acc[0][1], 0, 0, 0);
            acc[1][0] = __builtin_amdgcn_mfma_f32_16x16x32_bf16(a1, b0, acc[1][0], 0, 0, 0);
            acc[1][1] = __builtin_amdgcn_mfma_f32_16x16x32_bf16(a1, b1, acc[1][1], 0, 0, 0);
        }
    }

    if (mode == 0) {
        float* C = (float*)Cout;
#pragma unroll
        for (int mt = 0; mt < 2; ++mt)
#pragma unroll
        for (int nt = 0; nt < 2; ++nt)
#pragma unroll
        for (int j = 0; j < 4; ++j) {
            const int r = bm + mrow + mt * 16 + lg * 4 + j;
            const int c = bn + ncol + nt * 16 + lr;
            C[(size_t)r * DMODEL + c] = acc[mt][nt][j] * scale + (bias ? bias[c] : 0.f);
        }
    } else if (mode == 1) {
        unsigned short* C = (unsigned short*)Cout;
#pragma unroll
        for (int mt = 0; mt < 2; ++mt)
#pragma unroll
        for (int nt = 0; nt < 2; ++nt)
#pragma unroll
        for (int j = 0; j < 4; ++j) {
            const int r = bm + mrow + mt * 16 + lg * 4 + j;
            const int c = bn + ncol + nt * 16 + lr;
            const float v = acc[mt][nt][j] * scale + (bias ? bias[c] : 0.f);
            const int b = r >> 10, ll = r & (SEQ - 1);
            const int h = c >> 6, dd = c & 63;
            C[((size_t)(b * NHEADS + h) * SEQ + ll) * DHEAD + dd] = f2bf(v);
        }
    } else {
        // mode 2: Vt[((b*8+h)*64+dd)*1024 + l], j -> consecutive l
        unsigned short* C = (unsigned short*)Cout;
#pragma unroll
        for (int mt = 0; mt < 2; ++mt)
#pragma unroll
        for (int nt = 0; nt < 2; ++nt) {
            const int c = bn + ncol + nt * 16 + lr;
            const int h = c >> 6, dd = c & 63;
            const int r0 = bm + mrow + mt * 16 + lg * 4;   // 4-aligned
            const int b = r0 >> 10, l0 = r0 & (SEQ - 1);
            unsigned short tmp[4];
#pragma unroll
            for (int j = 0; j < 4; ++j)
                tmp[j] = f2bf(acc[mt][nt][j] * scale + (bias ? bias[c] : 0.f));
            *(uint2*)&C[((size_t)(b * NHEADS + h) * DHEAD + dd) * SEQ + l0] =
                *(const uint2*)tmp;
        }
    }
}

// ---------------------------------------------------------------------------
// MFMA sparsemax attention. Block = 16 q-rows of one (b,h); 4 waves (256 thr).
// Wave w: QK^T key slice w*256 -> S f32 LDS; Newton tau rows 4w..4w+3;
// PV d-cols w*16 over all keys, V read as B-frags from GLOBAL Vt[b][h][d][l]
// (L2-resident via XCD swizzle). Exactly 2 barriers per block.
// ---------------------------------------------------------------------------
__global__ __launch_bounds__(256, 2) void attn_mfma(
    const unsigned short* __restrict__ Q, const unsigned short* __restrict__ K,
    const unsigned short* __restrict__ Vt, unsigned short* __restrict__ R)
{
    __shared__ __align__(16) float S[QBLK][SPAD];
    __shared__ float tau_s[QBLK];

    const int tid = threadIdx.x;
    const int w = tid >> 6, l = tid & 63, lr = l & 15, lg = l >> 4;

    // XCD-aware decode: 4096 blocks, xcd = flat&7 owns 8 consecutive (b,h)
    const int flat = blockIdx.x;
    const int nid = (flat & 7) * 512 + (flat >> 3);
    const int q0 = (nid & 63) * QBLK;
    const int h = (nid >> 6) & (NHEADS - 1);
    const int b = nid >> 9;

    const size_t base = (size_t)(b * NHEADS + h) * SEQ * DHEAD;
    const unsigned short* Qp = Q + base;
    const unsigned short* Kp = K + base;

    const int ks = w * 256;   // wave's QK key slice

    // ---- QK^T (validated contract); Q pre-scaled by 1/TEMPERATURE ----
    const bf16x8 aq0 = *(const bf16x8*)(Qp + (size_t)(q0 + lr) * DHEAD + lg * 8);
    const bf16x8 aq1 = *(const bf16x8*)(Qp + (size_t)(q0 + lr) * DHEAD + 32 + lg * 8);
    {
        f32x4 acc[16];
#pragma unroll
        for (int t = 0; t < 16; ++t) acc[t] = (f32x4)0.f;
#pragma unroll 4
        for (int t = 0; t < 16; ++t) {
            const unsigned short* kp = Kp + (size_t)(ks + t * 16 + lr) * DHEAD + lg * 8;
            const bf16x8 bk0 = *(const bf16x8*)(kp);
            const bf16x8 bk1 = *(const bf16x8*)(kp + 32);
            acc[t] = __builtin_amdgcn_mfma_f32_16x16x32_bf16(aq0, bk0, acc[t], 0, 0, 0);
            acc[t] = __builtin_amdgcn_mfma_f32_16x16x32_bf16(aq1, bk1, acc[t], 0, 0, 0);
        }
#pragma unroll
        for (int t = 0; t < 16; ++t)
#pragma unroll
            for (int j = 0; j < 4; ++j)
                S[lg * 4 + j][ks + t * 16 + lr] = acc[t][j];
    }
    __syncthreads();   // S complete

    // ---- sparsemax tau (exact Newton, monotone from max-1): wave w rows 4w..4w+3
    for (int rr = 0; rr < 4; ++rr) {
        const int r = w * 4 + rr;
        float z[16];
#pragma unroll
        for (int j = 0; j < 16; ++j) z[j] = S[r][l + j * 64];
        float m = z[0];
#pragma unroll
        for (int j = 1; j < 16; ++j) m = fmaxf(m, z[j]);
#pragma unroll
        for (int o = 32; o >= 1; o >>= 1) m = fmaxf(m, __shfl_xor(m, o));
        float tau = m - 1.0f;
        for (int it = 0; it < 32; ++it) {
            float s = 0.f, cnt = 0.f;
#pragma unroll
            for (int j = 0; j < 16; ++j)
                if (z[j] > tau) { s += z[j]; cnt += 1.f; }
#pragma unroll
            for (int o = 32; o >= 1; o >>= 1) {
                s += __shfl_xor(s, o);
                cnt += __shfl_xor(cnt, o);
            }
            const float tn = (s - 1.f) / cnt;   // cnt >= 1 always (tau < row max)
            if (tn == tau) break;
            tau = tn;
        }
        if (l == 0) tau_s[r] = tau;
    }
    __syncthreads();   // tau ready — last barrier in the kernel

    // ---- PV: wave w owns d-cols w*16..w*16+15; V B-frags straight from L2 ----
    const float taur = tau_s[lr];
    const int dcol = w * 16;
    const unsigned short* VtP = Vt + ((size_t)(b * NHEADS + h) * DHEAD + dcol + lr) * SEQ
                                + lg * 8;
    f32x4 o = (f32x4)0.f;
    bf16x8 vb = *(const bf16x8*)(VtP);
#pragma unroll 4
    for (int kt = 0; kt < 32; ++kt) {
        const bf16x8 vcur = vb;
        if (kt + 1 < 32) vb = *(const bf16x8*)(VtP + (kt + 1) * 32);
        const float* sp = &S[lr][kt * 32 + lg * 8];
        const f32x4 s0 = *(const f32x4*)sp;
        const f32x4 s1 = *(const f32x4*)(sp + 4);
        bf16x8 pa;
#pragma unroll
        for (int i = 0; i < 4; ++i) {
            pa[i]     = (short)f2bf(fmaxf(s0[i] - taur, 0.f));
            pa[i + 4] = (short)f2bf(fmaxf(s1[i] - taur, 0.f));
        }
        __builtin_amdgcn_s_setprio(1);
        o = __builtin_amdgcn_mfma_f32_16x16x32_bf16(pa, vcur, o, 0, 0, 0);
        __builtin_amdgcn_s_setprio(0);
    }

    // ---- write O tile rows q0+lg*4+j, cols h*64+dcol+lr (bf16 for final GEMM)
#pragma unroll
    for (int j = 0; j < 4; ++j)
        R[((size_t)b * SEQ + q0 + lg * 4 + j) * DMODEL + h * DHEAD + dcol + lr] =
            f2bf(o[j]);
}

extern "C" void kernel_launch(void* const* d_in, const int* in_sizes, int n_in,
                              void* d_out, int out_size, void* d_ws, size_t ws_size,
                              hipStream_t stream) {
    const float* h_q = (const float*)d_in[0];
    const float* h_k = (const float*)d_in[1];
    const float* h_v = (const float*)d_in[2];
    const float* Wq  = (const float*)d_in[3];
    const float* Wk  = (const float*)d_in[4];
    const float* Wv  = (const float*)d_in[5];
    const float* bv  = (const float*)d_in[6];
    const float* Wf  = (const float*)d_in[7];
    const float* bf  = (const float*)d_in[8];
    float* out = (float*)d_out;

    const size_t perT = (size_t)BS * NHEADS * SEQ * DHEAD;   // 4,194,304 elements
    unsigned short* Qws = (unsigned short*)d_ws;             // bf16 head layout
    unsigned short* Kws = Qws + perT;                        // bf16 head layout
    unsigned short* Vtw = Kws + perT;                        // bf16 transposed [b][h][d][l]
    unsigned short* Rws = Vtw + perT;                        // bf16 attn output

    const dim3 gemmGrid(DMODEL / 64, (BS * SEQ) / 64, 1);    // 8 x 128
    const dim3 attnGrid(BS * NHEADS * (SEQ / QBLK), 1, 1);   // 4096, XCD-decoded in-kernel

    mfma_gemm<<<gemmGrid, 256, 0, stream>>>(h_q, Wq, nullptr, Qws, 1, 0.125f, 0);
    mfma_gemm<<<gemmGrid, 256, 0, stream>>>(h_k, Wk, nullptr, Kws, 1, 1.0f, 0);
    mfma_gemm<<<gemmGrid, 256, 0, stream>>>(h_v, Wv, bv,      Vtw, 2, 1.0f, 0);
    attn_mfma<<<attnGrid, 256, 0, stream>>>(Qws, Kws, Vtw, Rws);
    mfma_gemm<<<gemmGrid, 256, 0, stream>>>(Rws, Wf, bf, out, 0, 1.0f, 1);
}

// Round 6
// 189.217 us; speedup vs baseline: 8.1415x; 2.0497x over previous
//
#include <hip/hip_runtime.h>
#include <hip/hip_bf16.h>
#include <cstdint>
#include <cstddef>

#define BS 8
#define SEQ 1024
#define DMODEL 512
#define NHEADS 8
#define DHEAD 64
#define QBLK 16
#define PPAD 1032   // P bf16 row stride (elems): 16B-aligned, non-pathological banks

typedef float f32x4 __attribute__((ext_vector_type(4)));
typedef short bf16x8 __attribute__((ext_vector_type(8)));

static __device__ __forceinline__ unsigned short f2bf(float v) {
    __hip_bfloat16 hb = __float2bfloat16(v);
    return *reinterpret_cast<unsigned short*>(&hb);
}

// ---------------------------------------------------------------------------
// f32 -> bf16 conversion pre-pass (7 independent jobs, blockIdx.y selects)
// ---------------------------------------------------------------------------
struct CvtJob { const float* s; unsigned short* d; int n4; };

__global__ __launch_bounds__(256) void cvt_many(
    CvtJob j0, CvtJob j1, CvtJob j2, CvtJob j3, CvtJob j4, CvtJob j5, CvtJob j6)
{
    CvtJob j;
    switch (blockIdx.y) {
        case 0: j = j0; break; case 1: j = j1; break; case 2: j = j2; break;
        case 3: j = j3; break; case 4: j = j4; break; case 5: j = j5; break;
        default: j = j6; break;
    }
    for (int i = blockIdx.x * 256 + threadIdx.x; i < j.n4; i += gridDim.x * 256) {
        const float4 f = ((const float4*)j.s)[i];
        uint2 u;
        u.x = (unsigned)f2bf(f.x) | ((unsigned)f2bf(f.y) << 16);
        u.y = (unsigned)f2bf(f.z) | ((unsigned)f2bf(f.w) << 16);
        ((uint2*)j.d)[i] = u;
    }
}

// ---------------------------------------------------------------------------
// bf16 MFMA GEMM, tile 64M x 128N, BK=64, global_load_lds staging with
// XOR source-swizzle (chunk c8 ^= r&7) so frag ds_read_b128 is conflict-free.
// C[r][c] = sum_k A[r][k]*W[c][k]; epilogue modes as validated in r5:
//  0: f32 row-major [M][512] + bias
//  1: bf16 head layout [b][h][l][dd], *scale (+bias)
//  2: bf16 transposed head layout [b][h][dd][l] (+bias)  [uint2 stores]
// ---------------------------------------------------------------------------
struct GArgs { const unsigned short* A; const unsigned short* W;
               const float* bias; void* C; float scale; int mode; };

__global__ __launch_bounds__(256) void gemm_mfma(GArgs g0, GArgs g1, GArgs g2) {
    __shared__ __align__(16) unsigned short As[64 * 64];
    __shared__ __align__(16) unsigned short Bs[128 * 64];

    const GArgs g = (blockIdx.z == 0) ? g0 : ((blockIdx.z == 1) ? g1 : g2);
    const int tid = threadIdx.x;
    const int w = tid >> 6, l = tid & 63, lr = l & 15, lg = l >> 4;
    const int bm = blockIdx.y * 64, bn = blockIdx.x * 128;
    const int mrow = (w & 1) * 32, ncol = (w >> 1) * 64;

    f32x4 acc[2][4];
#pragma unroll
    for (int mt = 0; mt < 2; ++mt)
#pragma unroll
        for (int nt = 0; nt < 4; ++nt) acc[mt][nt] = (f32x4)0.f;

    for (int k0 = 0; k0 < DMODEL; k0 += 64) {
        // stage A (64 rows): 2 instrs; each wave covers 8 rows (lane*16B linear)
#pragma unroll
        for (int i = 0; i < 2; ++i) {
            const int rbase = i * 32 + w * 8;
            const int r = rbase + (l >> 3);
            const unsigned short* src = g.A + (size_t)(bm + r) * DMODEL + k0
                                        + 8 * ((l & 7) ^ (r & 7));
            __builtin_amdgcn_global_load_lds((const unsigned int*)src,
                                             (unsigned int*)&As[rbase * 64], 16, 0, 0);
        }
        // stage B (128 rows): 4 instrs
#pragma unroll
        for (int i = 0; i < 4; ++i) {
            const int rbase = i * 32 + w * 8;
            const int r = rbase + (l >> 3);
            const unsigned short* src = g.W + (size_t)(bn + r) * DMODEL + k0
                                        + 8 * ((l & 7) ^ (r & 7));
            __builtin_amdgcn_global_load_lds((const unsigned int*)src,
                                             (unsigned int*)&Bs[rbase * 64], 16, 0, 0);
        }
        __syncthreads();   // vmcnt(0) drained before barrier -> LDS tiles ready
#pragma unroll
        for (int kk = 0; kk < 2; ++kk) {
            bf16x8 av[2], bv[4];
#pragma unroll
            for (int mt = 0; mt < 2; ++mt) {
                const int ra = mrow + mt * 16 + lr;
                av[mt] = *(const bf16x8*)&As[ra * 64 + 8 * ((kk * 4 + lg) ^ (ra & 7))];
            }
#pragma unroll
            for (int nt = 0; nt < 4; ++nt) {
                const int rb = ncol + nt * 16 + lr;
                bv[nt] = *(const bf16x8*)&Bs[rb * 64 + 8 * ((kk * 4 + lg) ^ (rb & 7))];
            }
#pragma unroll
            for (int mt = 0; mt < 2; ++mt)
#pragma unroll
                for (int nt = 0; nt < 4; ++nt)
                    acc[mt][nt] = __builtin_amdgcn_mfma_f32_16x16x32_bf16(
                        av[mt], bv[nt], acc[mt][nt], 0, 0, 0);
        }
        __syncthreads();   // protect LDS before next-tile overwrite
    }

    if (g.mode == 0) {
        float* C = (float*)g.C;
#pragma unroll
        for (int mt = 0; mt < 2; ++mt)
#pragma unroll
        for (int nt = 0; nt < 4; ++nt)
#pragma unroll
        for (int j = 0; j < 4; ++j) {
            const int r = bm + mrow + mt * 16 + lg * 4 + j;
            const int c = bn + ncol + nt * 16 + lr;
            C[(size_t)r * DMODEL + c] = acc[mt][nt][j] * g.scale
                                        + (g.bias ? g.bias[c] : 0.f);
        }
    } else if (g.mode == 1) {
        unsigned short* C = (unsigned short*)g.C;
#pragma unroll
        for (int mt = 0; mt < 2; ++mt)
#pragma unroll
        for (int nt = 0; nt < 4; ++nt)
#pragma unroll
        for (int j = 0; j < 4; ++j) {
            const int r = bm + mrow + mt * 16 + lg * 4 + j;
            const int c = bn + ncol + nt * 16 + lr;
            const float v = acc[mt][nt][j] * g.scale + (g.bias ? g.bias[c] : 0.f);
            const int b = r >> 10, ll = r & (SEQ - 1);
            const int h = c >> 6, dd = c & 63;
            C[((size_t)(b * NHEADS + h) * SEQ + ll) * DHEAD + dd] = f2bf(v);
        }
    } else {
        unsigned short* C = (unsigned short*)g.C;
#pragma unroll
        for (int mt = 0; mt < 2; ++mt)
#pragma unroll
        for (int nt = 0; nt < 4; ++nt) {
            const int c = bn + ncol + nt * 16 + lr;
            const int h = c >> 6, dd = c & 63;
            const int r0 = bm + mrow + mt * 16 + lg * 4;
            const int b = r0 >> 10, l0 = r0 & (SEQ - 1);
            unsigned short tmp[4];
#pragma unroll
            for (int j = 0; j < 4; ++j)
                tmp[j] = f2bf(acc[mt][nt][j] * g.scale + (g.bias ? g.bias[c] : 0.f));
            uint2 u;
            u.x = (unsigned)tmp[0] | ((unsigned)tmp[1] << 16);
            u.y = (unsigned)tmp[2] | ((unsigned)tmp[3] << 16);
            *(uint2*)&C[((size_t)(b * NHEADS + h) * DHEAD + dd) * SEQ + l0] = u;
        }
    }
}

// ---------------------------------------------------------------------------
// MFMA sparsemax attention, register-resident scores.
// Block = 16 q-rows of one (b,h); 4 waves. Wave w: QK^T key slice w*256 kept
// in acc regs. Hierarchical row-max + Newton tau (in-reg partials, shfl_xor
// over lr, LDS cross-wave combine; 2 barriers/iter, uniform early break).
// P = relu(acc - tau) written ONCE as bf16 to LDS (33 KB -> 4 blocks/CU);
// PV reads A-frags as ds_read_b128, V as B-frags from global Vt[b][h][d][l].
// ---------------------------------------------------------------------------
__global__ __launch_bounds__(256, 4) void attn_mfma(
    const unsigned short* __restrict__ Q, const unsigned short* __restrict__ K,
    const unsigned short* __restrict__ Vt, unsigned short* __restrict__ R)
{
    __shared__ __align__(16) unsigned short P[QBLK][PPAD];
    __shared__ float red_s[4][QBLK];
    __shared__ float red_c[4][QBLK];

    const int tid = threadIdx.x;
    const int w = tid >> 6, l = tid & 63, lr = l & 15, lg = l >> 4;

    // XCD-aware decode: xcd = flat&7 owns 512 consecutive nids (8 (b,h) pairs)
    const int flat = blockIdx.x;
    const int nid = (flat & 7) * 512 + (flat >> 3);
    const int q0 = (nid & 63) * QBLK;
    const int h = (nid >> 6) & (NHEADS - 1);
    const int b = nid >> 9;

    const size_t base = (size_t)(b * NHEADS + h) * SEQ * DHEAD;
    const unsigned short* Qp = Q + base;
    const unsigned short* Kp = K + base;

    const int ks = w * 256;   // wave's key slice

    // ---- QK^T into registers (validated contract); Q pre-scaled 1/8 ----
    const bf16x8 aq0 = *(const bf16x8*)(Qp + (size_t)(q0 + lr) * DHEAD + lg * 8);
    const bf16x8 aq1 = *(const bf16x8*)(Qp + (size_t)(q0 + lr) * DHEAD + 32 + lg * 8);
    f32x4 acc[16];
#pragma unroll
    for (int t = 0; t < 16; ++t) acc[t] = (f32x4)0.f;
#pragma unroll
    for (int t = 0; t < 16; ++t) {
        const unsigned short* kp = Kp + (size_t)(ks + t * 16 + lr) * DHEAD + lg * 8;
        const bf16x8 bk0 = *(const bf16x8*)(kp);
        const bf16x8 bk1 = *(const bf16x8*)(kp + 32);
        acc[t] = __builtin_amdgcn_mfma_f32_16x16x32_bf16(aq0, bk0, acc[t], 0, 0, 0);
        acc[t] = __builtin_amdgcn_mfma_f32_16x16x32_bf16(aq1, bk1, acc[t], 0, 0, 0);
    }
    // lane holds S[rows lg*4+j][cols ks + t*16 + lr], j=0..3

    // ---- hierarchical row max ----
    float mx[4];
#pragma unroll
    for (int j = 0; j < 4; ++j) mx[j] = acc[0][j];
#pragma unroll
    for (int t = 1; t < 16; ++t)
#pragma unroll
        for (int j = 0; j < 4; ++j) mx[j] = fmaxf(mx[j], acc[t][j]);
#pragma unroll
    for (int o = 1; o < 16; o <<= 1)
#pragma unroll
        for (int j = 0; j < 4; ++j) mx[j] = fmaxf(mx[j], __shfl_xor(mx[j], o));
    if (lr == 0) {
#pragma unroll
        for (int j = 0; j < 4; ++j) red_s[w][lg * 4 + j] = mx[j];
    }
    __syncthreads();
    float tau[4];
#pragma unroll
    for (int j = 0; j < 4; ++j) {
        const int r = lg * 4 + j;
        tau[j] = fmaxf(fmaxf(red_s[0][r], red_s[1][r]),
                       fmaxf(red_s[2][r], red_s[3][r])) - 1.0f;
    }
    __syncthreads();   // red buffer free for Newton writes

    // ---- Newton on tau (exact, monotone from max-1, uniform early break) ----
    for (int it = 0; it < 32; ++it) {
        float s[4] = {0.f, 0.f, 0.f, 0.f};
        float c[4] = {0.f, 0.f, 0.f, 0.f};
#pragma unroll
        for (int t = 0; t < 16; ++t)
#pragma unroll
            for (int j = 0; j < 4; ++j) {
                const bool ggt = acc[t][j] > tau[j];
                s[j] += ggt ? acc[t][j] : 0.f;
                c[j] += ggt ? 1.f : 0.f;
            }
#pragma unroll
        for (int o = 1; o < 16; o <<= 1)
#pragma unroll
            for (int j = 0; j < 4; ++j) {
                s[j] += __shfl_xor(s[j], o);
                c[j] += __shfl_xor(c[j], o);
            }
        if (lr == 0) {
#pragma unroll
            for (int j = 0; j < 4; ++j) {
                red_s[w][lg * 4 + j] = s[j];
                red_c[w][lg * 4 + j] = c[j];
            }
        }
        __syncthreads();
        bool stable = true;
#pragma unroll
        for (int j = 0; j < 4; ++j) {
            const int r = lg * 4 + j;
            const float st = red_s[0][r] + red_s[1][r] + red_s[2][r] + red_s[3][r];
            const float ct = red_c[0][r] + red_c[1][r] + red_c[2][r] + red_c[3][r];
            const float tn = (st - 1.f) / ct;   // ct >= 1 always (tau < row max)
            stable = stable && (tn == tau[j]);
            tau[j] = tn;
        }
        const int done = __all(stable ? 1 : 0);   // identical across all waves
        __syncthreads();   // red free for next iteration
        if (done) break;
    }

    // ---- write P = relu(acc - tau) as bf16 (the PV A operand) ----
#pragma unroll
    for (int t = 0; t < 16; ++t)
#pragma unroll
        for (int j = 0; j < 4; ++j)
            P[lg * 4 + j][ks + t * 16 + lr] = f2bf(fmaxf(acc[t][j] - tau[j], 0.f));
    __syncthreads();   // P complete — last barrier

    // ---- PV: wave w owns d-cols w*16..+15; V B-frags from global Vt ----
    const int dcol = w * 16;
    const unsigned short* VtP = Vt + ((size_t)(b * NHEADS + h) * DHEAD + dcol + lr) * SEQ
                                + lg * 8;
    f32x4 o = (f32x4)0.f;
    bf16x8 vb = *(const bf16x8*)(VtP);
#pragma unroll 4
    for (int kt = 0; kt < 32; ++kt) {
        const bf16x8 vcur = vb;
        if (kt + 1 < 32) vb = *(const bf16x8*)(VtP + (kt + 1) * 32);
        const bf16x8 pa = *(const bf16x8*)&P[lr][kt * 32 + lg * 8];
        __builtin_amdgcn_s_setprio(1);
        o = __builtin_amdgcn_mfma_f32_16x16x32_bf16(pa, vcur, o, 0, 0, 0);
        __builtin_amdgcn_s_setprio(0);
    }

    // ---- write O tile rows q0+lg*4+j, cols h*64+dcol+lr (bf16 for final GEMM)
#pragma unroll
    for (int j = 0; j < 4; ++j)
        R[((size_t)b * SEQ + q0 + lg * 4 + j) * DMODEL + h * DHEAD + dcol + lr] =
            f2bf(o[j]);
}

extern "C" void kernel_launch(void* const* d_in, const int* in_sizes, int n_in,
                              void* d_out, int out_size, void* d_ws, size_t ws_size,
                              hipStream_t stream) {
    const float* h_q = (const float*)d_in[0];
    const float* h_k = (const float*)d_in[1];
    const float* h_v = (const float*)d_in[2];
    const float* Wq  = (const float*)d_in[3];
    const float* Wk  = (const float*)d_in[4];
    const float* Wv  = (const float*)d_in[5];
    const float* bv  = (const float*)d_in[6];
    const float* Wf  = (const float*)d_in[7];
    const float* bf  = (const float*)d_in[8];
    float* out = (float*)d_out;

    const size_t perT = (size_t)BS * SEQ * DMODEL;   // 4,194,304 elements
    const size_t wN = (size_t)DMODEL * DMODEL;       // 262,144 elements
    unsigned short* hq_b = (unsigned short*)d_ws;    // bf16 inputs
    unsigned short* hk_b = hq_b + perT;
    unsigned short* hv_b = hk_b + perT;
    unsigned short* Qws  = hv_b + perT;              // projections (head layout)
    unsigned short* Kws  = Qws + perT;
    unsigned short* Vtw  = Kws + perT;               // transposed [b][h][d][l]
    unsigned short* Rws  = Vtw + perT;               // attn output (bf16)
    unsigned short* Wqb  = Rws + perT;               // bf16 weights
    unsigned short* Wkb  = Wqb + wN;
    unsigned short* Wvb  = Wkb + wN;
    unsigned short* Wfb  = Wvb + wN;

    // 1) convert inputs + weights to bf16
    {
        CvtJob j0{h_q, hq_b, (int)(perT / 4)};
        CvtJob j1{h_k, hk_b, (int)(perT / 4)};
        CvtJob j2{h_v, hv_b, (int)(perT / 4)};
        CvtJob j3{Wq, Wqb, (int)(wN / 4)};
        CvtJob j4{Wk, Wkb, (int)(wN / 4)};
        CvtJob j5{Wv, Wvb, (int)(wN / 4)};
        CvtJob j6{Wf, Wfb, (int)(wN / 4)};
        cvt_many<<<dim3(512, 7), 256, 0, stream>>>(j0, j1, j2, j3, j4, j5, j6);
    }

    // 2) fused Q/K/V projections (bf16 MFMA, gload_lds staging)
    {
        GArgs gq{hq_b, Wqb, nullptr, Qws, 0.125f, 1};
        GArgs gk{hk_b, Wkb, nullptr, Kws, 1.0f, 1};
        GArgs gv{hv_b, Wvb, bv,      Vtw, 1.0f, 2};
        gemm_mfma<<<dim3(DMODEL / 128, BS * SEQ / 64, 3), 256, 0, stream>>>(gq, gk, gv);
    }

    // 3) attention
    attn_mfma<<<dim3(BS * NHEADS * (SEQ / QBLK)), 256, 0, stream>>>(Qws, Kws, Vtw, Rws);

    // 4) output projection
    {
        GArgs gf{Rws, Wfb, bf, out, 1.0f, 0};
        gemm_mfma<<<dim3(DMODEL / 128, BS * SEQ / 64, 1), 256, 0, stream>>>(gf, gf, gf);
    }
}